// Round 3
// baseline (639.999 us; speedup 1.0000x reference)
//
#include <hip/hip_runtime.h>
#include <stdint.h>

typedef unsigned long long u64;
typedef unsigned int u32;

#define NB   4000   // boxes
#define NBP  4096   // padded to pow2
#define NCLS 80     // foreground classes
#define ROWW 64     // u64 words per suppression row (4096 bits)
#define MAXI 100    // max instances

__device__ __forceinline__ u32 mono_f32(float f) {
    u32 u = __float_as_uint(f);
    return (u & 0x80000000u) ? ~u : (u | 0x80000000u);
}

// ---------------- K1: pairwise suppression bitmap ----------------
__global__ __launch_bounds__(256) void k_suppr(const float* __restrict__ boxes,
                                               const float* __restrict__ nms_t,
                                               u64* __restrict__ suppr) {
    const int i = blockIdx.y;
    const int j = blockIdx.x * 256 + threadIdx.x;
    const float t = *nms_t;
    const float x1i = boxes[i*4+0], y1i = boxes[i*4+1];
    const float x2i = boxes[i*4+2], y2i = boxes[i*4+3];
    bool bit = false;
    if (j < NB && j != i) {
        const float x1j = boxes[j*4+0], y1j = boxes[j*4+1];
        const float x2j = boxes[j*4+2], y2j = boxes[j*4+3];
        const float ai = (x2i - x1i) * (y2i - y1i);
        const float aj = (x2j - x1j) * (y2j - y1j);
        const float ix1 = fmaxf(x1i, x1j), iy1 = fmaxf(y1i, y1j);
        const float ix2 = fminf(x2i, x2j), iy2 = fminf(y2i, y2j);
        const float inter = fmaxf(ix2 - ix1, 0.0f) * fmaxf(iy2 - iy1, 0.0f);
        const float iou = inter / (ai + aj - inter + 1e-9f);
        bit = iou > t;
    }
    const u64 m = __ballot(bit);
    if ((threadIdx.x & 63) == 0) suppr[(size_t)i * ROWW + (j >> 6)] = m;
}

// ---------------- K2: per-class sort + greedy NMS walk ----------------
__global__ __launch_bounds__(256) void k_classnms(const float* __restrict__ scores,
                                                  const float* __restrict__ conf_t,
                                                  const u64* __restrict__ suppr,
                                                  u64* __restrict__ cand) {
    __shared__ u64 skey[NBP];
    __shared__ unsigned short sbox[NBP];
    __shared__ int sh_nvalid;
    __shared__ int sh_kept;

    const int c   = blockIdx.x;
    const int tid = threadIdx.x;
    const float conf = *conf_t;

    if (tid == 0) { sh_nvalid = 0; sh_kept = 0; }
    __syncthreads();

    int cnt = 0;
    for (int b = tid; b < NBP; b += 256) {
        u64 k = 0;
        if (b < NB) {
            const float s = scores[b * 81 + c + 1];   // scores[:, c+1]
            if (s > conf) {
                k = ((u64)mono_f32(s) << 32) | (u64)(0xFFFFFFFFu - (u32)b);
                cnt++;
            }
        }
        skey[b] = k;
    }
    atomicAdd(&sh_nvalid, cnt);

    // bitonic sort, descending; ties -> smaller box index first (stable argsort(-s))
    for (int k = 2; k <= NBP; k <<= 1) {
        for (int j = k >> 1; j > 0; j >>= 1) {
            __syncthreads();
            for (int i = tid; i < NBP; i += 256) {
                const int l = i ^ j;
                if (l > i) {
                    const u64 a = skey[i], b = skey[l];
                    const bool up = ((i & k) == 0);
                    if (up ? (a < b) : (a > b)) { skey[i] = b; skey[l] = a; }
                }
            }
        }
    }
    __syncthreads();

    const int nvalid = sh_nvalid;
    for (int i = tid; i < NBP; i += 256)
        sbox[i] = (unsigned short)(0xFFFFFFFFu - (u32)skey[i]);
    __syncthreads();

    // serial greedy walk on wave 0; kept-set as distributed 4096-bit mask
    if (tid < 64) {
        const int lane = tid;
        u64 keptmask = 0;
        int kept = 0;
        if (nvalid > 0) {
            int b = sbox[0];
            u64 w = suppr[(size_t)b * ROWW + lane];
            for (int p = 0; p < nvalid && kept < MAXI; ++p) {
                const int bn = (p + 1 < nvalid) ? (int)sbox[p + 1] : 0;
                const u64 wn = suppr[(size_t)bn * ROWW + lane];
                const bool suppressed = (__ballot((w & keptmask) != 0ull) != 0ull);
                if (!suppressed) {
                    if (lane == (b >> 6)) keptmask |= (1ull << (b & 63));
                    if (lane == 0) {
                        const u32 mono = (u32)(skey[p] >> 32);
                        const u32 flat = (u32)(c * NB + b);
                        cand[c * MAXI + kept] = ((u64)mono << 32) | (u64)(0xFFFFFFFFu - flat);
                    }
                    kept++;
                }
                b = bn; w = wn;
            }
        }
        if (lane == 0) sh_kept = kept;
    }
    __syncthreads();

    const int kept = sh_kept;
    for (int s = tid; s < MAXI; s += 256)
        if (s >= kept) cand[c * MAXI + s] = 0;
}

// ---------------- K3: global top-100 over 8000 candidate keys ----------------
// Two 4096-key bitonic sorts (32 KiB LDS); top-100 of the union lies within
// the top-128 of each sorted half, merged by a final 256-key bitonic sort.
__global__ __launch_bounds__(256) void k_topk(const u64* __restrict__ cand,
                                              const float* __restrict__ boxes,
                                              float* __restrict__ out) {
    __shared__ u64 key[4096];
    __shared__ u64 top[256];   // 128 from each half
    const int tid = threadIdx.x;

    for (int half = 0; half < 2; ++half) {
        __syncthreads();
        for (int i = tid; i < 4096; i += 256) {
            const int src = half * 4000 + i;
            key[i] = (i < 4000) ? cand[src] : 0ull;
        }
        for (int k = 2; k <= 4096; k <<= 1) {
            for (int j = k >> 1; j > 0; j >>= 1) {
                __syncthreads();
                for (int i = tid; i < 4096; i += 256) {
                    const int l = i ^ j;
                    if (l > i) {
                        const u64 a = key[i], b = key[l];
                        const bool up = ((i & k) == 0);
                        if (up ? (a < b) : (a > b)) { key[i] = b; key[l] = a; }
                    }
                }
            }
        }
        __syncthreads();
        if (tid < 128) top[half * 128 + tid] = key[tid];
    }

    // final 256-key bitonic sort, descending
    for (int k = 2; k <= 256; k <<= 1) {
        for (int j = k >> 1; j > 0; j >>= 1) {
            __syncthreads();
            {
                const int i = tid;
                const int l = i ^ j;
                if (l > i) {
                    const u64 a = top[i], b = top[l];
                    const bool up = ((i & k) == 0);
                    if (up ? (a < b) : (a > b)) { top[i] = b; top[l] = a; }
                }
            }
        }
    }
    __syncthreads();

    if (tid < MAXI) {
        const u64 kk = top[tid];
        const u32 mono = (u32)(kk >> 32);
        if (mono > 0x80000000u) {        // score > 0.0
            const float s = __uint_as_float(mono ^ 0x80000000u);
            const u32 flat = 0xFFFFFFFFu - (u32)kk;
            const int cls = (int)(flat / NB);
            const int b   = (int)(flat % NB);
            out[tid*5+0] = boxes[b*4+0];
            out[tid*5+1] = boxes[b*4+1];
            out[tid*5+2] = boxes[b*4+2];
            out[tid*5+3] = boxes[b*4+3];
            out[tid*5+4] = s;
            out[500 + tid] = (float)cls;
        } else {
            out[tid*5+0] = 0.0f; out[tid*5+1] = 0.0f; out[tid*5+2] = 0.0f;
            out[tid*5+3] = 0.0f; out[tid*5+4] = 0.0f;
            out[500 + tid] = -1.0f;
        }
    }
}

extern "C" void kernel_launch(void* const* d_in, const int* in_sizes, int n_in,
                              void* d_out, int out_size, void* d_ws, size_t ws_size,
                              hipStream_t stream) {
    const float* bboxes = (const float*)d_in[0];
    const float* scores = (const float*)d_in[1];
    const float* conf_t = (const float*)d_in[2];
    const float* nms_t  = (const float*)d_in[3];

    u64* suppr = (u64*)d_ws;                                  // 2,048,000 B
    u64* cand  = (u64*)((char*)d_ws + (size_t)NB * ROWW * 8); // 64,000 B

    dim3 g1(16, NB);
    k_suppr<<<g1, 256, 0, stream>>>(bboxes, nms_t, suppr);
    k_classnms<<<NCLS, 256, 0, stream>>>(scores, conf_t, suppr, cand);
    k_topk<<<1, 256, 0, stream>>>(cand, bboxes, (float*)d_out);
}

// Round 5
// 252.471 us; speedup vs baseline: 2.5349x; 2.5349x over previous
//
#include <hip/hip_runtime.h>
#include <stdint.h>

typedef unsigned long long u64;
typedef unsigned int u32;

#define NB   4000   // boxes
#define NBP  4096   // padded to pow2
#define NCLS 80     // foreground classes
#define ROWW 64     // u64 words per suppression row (4096 bits)
#define MAXI 100    // max instances
#define NKEY (NCLS * MAXI)   // 8000 candidate keys

__device__ __forceinline__ u32 mono_f32(float f) {
    u32 u = __float_as_uint(f);
    return (u & 0x80000000u) ? ~u : (u | 0x80000000u);
}

// ---------------- K1: pairwise suppression bitmap (one block per box i) ----
__global__ __launch_bounds__(256) void k_suppr(const float4* __restrict__ boxes,
                                               const float* __restrict__ nms_t,
                                               u64* __restrict__ suppr) {
    const int i   = blockIdx.x;
    const int tid = threadIdx.x;
    const float t = *nms_t;
    const float4 bi = boxes[i];
    const float ai = (bi.z - bi.x) * (bi.w - bi.y);
    #pragma unroll
    for (int ch = 0; ch < 16; ++ch) {
        const int j = ch * 256 + tid;
        bool bit = false;
        if (j < NB && j != i) {
            const float4 bj = boxes[j];
            const float aj = (bj.z - bj.x) * (bj.w - bj.y);
            const float ix1 = fmaxf(bi.x, bj.x), iy1 = fmaxf(bi.y, bj.y);
            const float ix2 = fminf(bi.z, bj.z), iy2 = fminf(bi.w, bj.w);
            const float inter = fmaxf(ix2 - ix1, 0.0f) * fmaxf(iy2 - iy1, 0.0f);
            const float iou = inter / (ai + aj - inter + 1e-9f);
            bit = iou > t;
        }
        const u64 m = __ballot(bit);
        if ((tid & 63) == 0) suppr[(size_t)i * ROWW + (j >> 6)] = m;
    }
}

// ---------------- K2: per-class compact + sort + greedy NMS walk -----------
__global__ __launch_bounds__(256) void k_classnms(const float* __restrict__ scores,
                                                  const float* __restrict__ conf_t,
                                                  const u64* __restrict__ suppr,
                                                  u64* __restrict__ cand) {
    __shared__ u64 skey[NBP];
    __shared__ unsigned short sbox[NBP];
    __shared__ int sh_cnt;
    __shared__ int sh_kept;

    const int c   = blockIdx.x;
    const int tid = threadIdx.x;
    const int lane = tid & 63;
    const float conf = *conf_t;

    if (tid == 0) { sh_cnt = 0; sh_kept = 0; }
    __syncthreads();

    // compact valid entries (wave-aggregated) into skey[0..nvalid)
    for (int b = tid; b < NB; b += 256) {
        const float s = scores[b * 81 + c + 1];   // scores[:, c+1]
        const bool valid = (s > conf);
        const u64 mask = __ballot(valid);
        int base = 0;
        if (lane == 0) base = atomicAdd(&sh_cnt, (int)__popcll(mask));
        base = __shfl(base, 0);
        if (valid) {
            const int off = (int)__popcll(mask & ((1ull << lane) - 1ull));
            skey[base + off] = ((u64)mono_f32(s) << 32) | (u64)(0xFFFFFFFFu - (u32)b);
        }
    }
    __syncthreads();
    const int nvalid = sh_cnt;

    int S = 1;
    while (S < nvalid) S <<= 1;           // sort size = next pow2 >= nvalid

    for (int i = nvalid + tid; i < S; i += 256) skey[i] = 0;   // pad
    __syncthreads();

    // bitonic sort descending, batched loads->stores (pairs disjoint per pass)
    for (int k = 2; k <= S; k <<= 1) {
        for (int j = k >> 1; j > 0; j >>= 1) {
            const int npair = S >> 1;
            u64 va[8], vb[8];
            #pragma unroll
            for (int r = 0; r < 8; ++r) {
                const int p = tid + r * 256;
                if (p < npair) {
                    const int i0 = ((p & ~(j - 1)) << 1) | (p & (j - 1));
                    va[r] = skey[i0];
                    vb[r] = skey[i0 | j];
                }
            }
            #pragma unroll
            for (int r = 0; r < 8; ++r) {
                const int p = tid + r * 256;
                if (p < npair) {
                    const int i0 = ((p & ~(j - 1)) << 1) | (p & (j - 1));
                    const bool up = ((i0 & k) == 0);
                    const u64 a = va[r], b = vb[r];
                    if (up ? (a < b) : (a > b)) { skey[i0] = b; skey[i0 | j] = a; }
                }
            }
            __syncthreads();
        }
    }

    for (int i = tid; i < S; i += 256)
        sbox[i] = (unsigned short)(0xFFFFFFFFu - (u32)skey[i]);
    __syncthreads();

    // serial greedy walk on wave 0; kept-set = distributed 4096-bit mask
    if (tid < 64) {
        u64 keptmask = 0;
        int kept = 0;
        if (nvalid > 0) {
            const int last = nvalid - 1;
            int i1 = (1 < nvalid) ? 1 : last;
            u64 w_cur = suppr[(size_t)sbox[0] * ROWW + lane];
            u64 w_n1  = suppr[(size_t)sbox[i1] * ROWW + lane];
            for (int p = 0; p < nvalid && kept < MAXI; ++p) {
                const int i2 = (p + 2 <= last) ? p + 2 : last;
                const u64 w_n2 = suppr[(size_t)sbox[i2] * ROWW + lane];
                const bool suppressed = (__ballot((w_cur & keptmask) != 0ull) != 0ull);
                if (!suppressed) {
                    const int b = sbox[p];
                    if (lane == (b >> 6)) keptmask |= (1ull << (b & 63));
                    if (lane == 0) {
                        const u32 mono = (u32)(skey[p] >> 32);
                        const u32 flat = (u32)(c * NB + b);
                        cand[c * MAXI + kept] = ((u64)mono << 32) | (u64)(0xFFFFFFFFu - flat);
                    }
                    kept++;
                }
                w_cur = w_n1; w_n1 = w_n2;
            }
        }
        if (lane == 0) sh_kept = kept;
    }
    __syncthreads();

    const int kept = sh_kept;
    for (int s = tid; s < MAXI; s += 256)
        if (s >= kept) cand[c * MAXI + s] = 0;
}

// ---------------- K3: rank-by-count top-100 (no sort) ----------------------
// Keys are unique (tie-broken by flat index) -> rank = #{keys > mine}.
// Block c ranks class c's <=100 candidates; rank<100 writes out[rank] directly.
__global__ __launch_bounds__(256) void k_rank(const u64* __restrict__ cand,
                                              const float4* __restrict__ boxes,
                                              float* __restrict__ out) {
    __shared__ u64 keys[NKEY];            // 64,000 B
    __shared__ int sh_T;
    const int c   = blockIdx.x;
    const int tid = threadIdx.x;

    if (tid == 0) sh_T = 0;
    for (int i = tid; i < NKEY; i += 256) keys[i] = cand[i];
    __syncthreads();

    // 2 threads per candidate: tid = 2*ci + half
    if (tid < 2 * MAXI) {
        const int ci   = tid >> 1;
        const int half = tid & 1;
        const u64 mine = keys[c * MAXI + ci];
        if (mine != 0ull) {
            int part = 0;
            const int beg = half * (NKEY / 2), end = beg + (NKEY / 2);
            #pragma unroll 8
            for (int i = beg; i < end; ++i) part += (keys[i] > mine);
            const int rank = part + __shfl_xor(part, 1);
            if (half == 0 && rank < MAXI) {
                const u32 mono = (u32)(mine >> 32);
                if (mono > 0x80000000u) {          // score > 0.0
                    const float s  = __uint_as_float(mono ^ 0x80000000u);
                    const u32 flat = 0xFFFFFFFFu - (u32)mine;
                    const int b    = (int)(flat % NB);
                    const float4 bb = boxes[b];
                    out[rank*5+0] = bb.x; out[rank*5+1] = bb.y;
                    out[rank*5+2] = bb.z; out[rank*5+3] = bb.w;
                    out[rank*5+4] = s;
                    out[500 + rank] = (float)(flat / NB);
                } else {                            // occupies rank but filtered
                    out[rank*5+0] = 0.0f; out[rank*5+1] = 0.0f; out[rank*5+2] = 0.0f;
                    out[rank*5+3] = 0.0f; out[rank*5+4] = 0.0f;
                    out[500 + rank] = -1.0f;
                }
            }
        }
    }

    // block 0: fill default rows [T, 100)
    if (c == 0) {
        int cnt = 0;
        for (int i = tid; i < NKEY; i += 256) cnt += (keys[i] != 0ull);
        atomicAdd(&sh_T, cnt);
        __syncthreads();
        const int T = sh_T;
        for (int r = T + tid; r < MAXI; r += 256) {
            out[r*5+0] = 0.0f; out[r*5+1] = 0.0f; out[r*5+2] = 0.0f;
            out[r*5+3] = 0.0f; out[r*5+4] = 0.0f;
            out[500 + r] = -1.0f;
        }
    }
}

extern "C" void kernel_launch(void* const* d_in, const int* in_sizes, int n_in,
                              void* d_out, int out_size, void* d_ws, size_t ws_size,
                              hipStream_t stream) {
    const float4* bboxes = (const float4*)d_in[0];
    const float*  scores = (const float*)d_in[1];
    const float*  conf_t = (const float*)d_in[2];
    const float*  nms_t  = (const float*)d_in[3];

    u64* suppr = (u64*)d_ws;                                  // 2,048,000 B
    u64* cand  = (u64*)((char*)d_ws + (size_t)NB * ROWW * 8); // 64,000 B

    k_suppr<<<NB, 256, 0, stream>>>(bboxes, nms_t, suppr);
    k_classnms<<<NCLS, 256, 0, stream>>>(scores, conf_t, suppr, cand);
    k_rank<<<NCLS, 256, 0, stream>>>(cand, bboxes, (float*)d_out);
}

// Round 7
// 238.627 us; speedup vs baseline: 2.6820x; 1.0580x over previous
//
#include <hip/hip_runtime.h>
#include <stdint.h>

typedef unsigned long long u64;
typedef unsigned int u32;

#define NB    4000            // boxes
#define NCLS  80              // foreground classes
#define ROWW  64              // u64 words per suppression row (4096 bits)
#define MAXI  100             // max instances
#define NKEY  (NCLS * MAXI)   // 8000 candidate keys
#define PCAP  4096            // per-class key-list capacity (stride)
#define SMAX  4096

__device__ __forceinline__ u32 mono_f32(float f) {
    u32 u = __float_as_uint(f);
    return (u & 0x80000000u) ? ~u : (u | 0x80000000u);
}

// ---------------- K0: compaction: scores -> per-class key lists ------------
__global__ __launch_bounds__(256) void k_compact(const float* __restrict__ scores,
                                                 const float* __restrict__ conf_t,
                                                 u64* __restrict__ pkeys,
                                                 int* __restrict__ gcnt) {
    const int b    = blockIdx.x * 256 + threadIdx.x;
    const int lane = threadIdx.x & 63;
    const float conf = *conf_t;
    const bool inb = (b < NB);
    for (int c = 0; c < NCLS; ++c) {
        const float s = inb ? scores[b * 81 + c + 1] : -1e30f;
        const bool valid = inb && (s > conf);
        const u64 mask = __ballot(valid);
        if (mask) {
            int base = 0;
            if (lane == 0) base = atomicAdd(&gcnt[c], (int)__popcll(mask));
            base = __shfl(base, 0);
            if (valid) {
                const int off = (int)__popcll(mask & ((1ull << lane) - 1ull));
                pkeys[c * PCAP + base + off] =
                    ((u64)mono_f32(s) << 32) | (u64)(0xFFFFFFFFu - (u32)b);
            }
        }
    }
}

// ---------------- K1: pairwise suppression bitmap (one block per box i) ----
__global__ __launch_bounds__(256) void k_suppr(const float4* __restrict__ boxes,
                                               const float* __restrict__ nms_t,
                                               u64* __restrict__ suppr) {
    const int i   = blockIdx.x;
    const int tid = threadIdx.x;
    const float t = *nms_t;
    const float4 bi = boxes[i];
    const float ai = (bi.z - bi.x) * (bi.w - bi.y);
    #pragma unroll
    for (int ch = 0; ch < 16; ++ch) {
        const int j = ch * 256 + tid;
        bool bit = false;
        if (j < NB && j != i) {
            const float4 bj = boxes[j];
            const float aj = (bj.z - bj.x) * (bj.w - bj.y);
            const float ix1 = fmaxf(bi.x, bj.x), iy1 = fmaxf(bi.y, bj.y);
            const float ix2 = fminf(bi.z, bj.z), iy2 = fminf(bi.w, bj.w);
            const float inter = fmaxf(ix2 - ix1, 0.0f) * fmaxf(iy2 - iy1, 0.0f);
            const float iou = inter / (ai + aj - inter + 1e-9f);
            bit = iou > t;
        }
        const u64 m = __ballot(bit);
        if ((tid & 63) == 0) suppr[(size_t)i * ROWW + (j >> 6)] = m;
    }
}

// ---------------- K2: per-class sort (LDS + shfl hybrid) + greedy walk -----
__global__ __launch_bounds__(1024) void k_classnms(const u64* __restrict__ pkeys,
                                                   const int* __restrict__ gcnt,
                                                   const u64* __restrict__ suppr,
                                                   u64* __restrict__ cand) {
    __shared__ u64 skey[SMAX];
    __shared__ unsigned short sbox[SMAX];
    __shared__ int sh_kept;

    const int c    = blockIdx.x;
    const int tid  = threadIdx.x;
    const int lane = tid & 63;

    const int nvalid = gcnt[c];
    int S = 64;
    while (S < nvalid) S <<= 1;           // 64..4096, multiple of 64

    if (tid == 0) sh_kept = 0;
    for (int i = tid; i < nvalid; i += 1024) skey[i] = pkeys[c * PCAP + i];
    for (int i = nvalid + tid; i < S; i += 1024) skey[i] = 0;
    __syncthreads();

    // bitonic sort descending: j>=64 in LDS (conflict-free), j<=32 via shfl
    for (int k2 = 2; k2 <= S; k2 <<= 1) {
        for (int j = k2 >> 1; j >= 64; j >>= 1) {
            for (int p = tid; p < (S >> 1); p += 1024) {
                const int i0 = ((p & ~(j - 1)) << 1) | (p & (j - 1));
                const u64 a = skey[i0], b = skey[i0 | j];
                const bool up = ((i0 & k2) == 0);
                if (up ? (a < b) : (a > b)) { skey[i0] = b; skey[i0 | j] = a; }
            }
            __syncthreads();
        }
        // in-register exchanges for j = 32..1
        for (int base = 0; base < S; base += 1024) {
            const int i = base + tid;
            if (i < S) {                   // S multiple of 64 -> whole waves
                u64 x = skey[i];
                #pragma unroll
                for (int j2 = 32; j2 >= 1; j2 >>= 1) {
                    if (j2 < k2) {
                        const u64 y = __shfl_xor(x, j2);
                        const bool wantmax = (((i & k2) == 0) == ((i & j2) == 0));
                        x = wantmax ? (x > y ? x : y) : (x < y ? x : y);
                    }
                }
                skey[i] = x;
            }
        }
        __syncthreads();
    }

    for (int i = tid; i < S; i += 1024)
        sbox[i] = (unsigned short)(0xFFFFFFFFu - (u32)skey[i]);
    __syncthreads();

    // serial greedy walk on wave 0; kept-set = distributed 4096-bit mask
    if (tid < 64) {
        u64 keptmask = 0;
        int kept = 0;
        if (nvalid > 0) {
            const int last = nvalid - 1;
            const int i1 = (1 <= last) ? 1 : last;
            u64 w_cur = suppr[(size_t)sbox[0] * ROWW + lane];
            u64 w_n1  = suppr[(size_t)sbox[i1] * ROWW + lane];
            for (int p = 0; p < nvalid && kept < MAXI; ++p) {
                const int i2 = (p + 2 <= last) ? p + 2 : last;
                const u64 w_n2 = suppr[(size_t)sbox[i2] * ROWW + lane];
                const bool suppressed = (__ballot((w_cur & keptmask) != 0ull) != 0ull);
                if (!suppressed) {
                    const int b = sbox[p];
                    if (lane == (b >> 6)) keptmask |= (1ull << (b & 63));
                    if (lane == 0) {
                        const u32 mono = (u32)(skey[p] >> 32);
                        const u32 flat = (u32)(c * NB + b);
                        cand[c * MAXI + kept] = ((u64)mono << 32) | (u64)(0xFFFFFFFFu - flat);
                    }
                    kept++;
                }
                w_cur = w_n1; w_n1 = w_n2;
            }
        }
        if (lane == 0) sh_kept = kept;
    }
    __syncthreads();

    const int kept = sh_kept;
    for (int s = tid; s < MAXI; s += 1024)
        if (s >= kept) cand[c * MAXI + s] = 0;
}

// ---------------- K3: rank-by-count top-100 (no sort) ----------------------
__global__ __launch_bounds__(1024) void k_rank(const u64* __restrict__ cand,
                                               const float4* __restrict__ boxes,
                                               float* __restrict__ out) {
    __shared__ u64 keys[NKEY];            // 64,000 B
    __shared__ int sh_T;
    const int c   = blockIdx.x;
    const int tid = threadIdx.x;

    if (tid == 0) sh_T = 0;
    for (int i = tid; i < NKEY; i += 1024) keys[i] = cand[i];
    __syncthreads();

    if (tid < 8 * MAXI) {
        const int ci   = tid >> 3;
        const int part = tid & 7;
        const u64 mine = keys[c * MAXI + ci];
        if (mine != 0ull) {
            int cnt = 0;
            #pragma unroll 8
            for (int m = 0; m < NKEY / 8; ++m)
                cnt += (keys[part + (m << 3)] > mine);
            cnt += __shfl_xor(cnt, 1);
            cnt += __shfl_xor(cnt, 2);
            cnt += __shfl_xor(cnt, 4);
            if (part == 0 && cnt < MAXI) {
                const int rank = cnt;
                const u32 mono = (u32)(mine >> 32);
                if (mono > 0x80000000u) {          // score > 0.0
                    const float s  = __uint_as_float(mono ^ 0x80000000u);
                    const u32 flat = 0xFFFFFFFFu - (u32)mine;
                    const int b    = (int)(flat % NB);
                    const float4 bb = boxes[b];
                    out[rank*5+0] = bb.x; out[rank*5+1] = bb.y;
                    out[rank*5+2] = bb.z; out[rank*5+3] = bb.w;
                    out[rank*5+4] = s;
                    out[500 + rank] = (float)(flat / NB);
                } else {
                    out[rank*5+0] = 0.0f; out[rank*5+1] = 0.0f; out[rank*5+2] = 0.0f;
                    out[rank*5+3] = 0.0f; out[rank*5+4] = 0.0f;
                    out[500 + rank] = -1.0f;
                }
            }
        }
    }

    // block 0: fill default rows [T, 100)
    if (c == 0) {
        int cnt = 0;
        for (int i = tid; i < NKEY; i += 1024) cnt += (keys[i] != 0ull);
        atomicAdd(&sh_T, cnt);
        __syncthreads();
        const int T = sh_T;
        for (int r = T + tid; r < MAXI; r += 1024) {
            out[r*5+0] = 0.0f; out[r*5+1] = 0.0f; out[r*5+2] = 0.0f;
            out[r*5+3] = 0.0f; out[r*5+4] = 0.0f;
            out[500 + r] = -1.0f;
        }
    }
}

extern "C" void kernel_launch(void* const* d_in, const int* in_sizes, int n_in,
                              void* d_out, int out_size, void* d_ws, size_t ws_size,
                              hipStream_t stream) {
    const float4* bboxes = (const float4*)d_in[0];
    const float*  scores = (const float*)d_in[1];
    const float*  conf_t = (const float*)d_in[2];
    const float*  nms_t  = (const float*)d_in[3];

    char* ws = (char*)d_ws;
    u64* suppr = (u64*)ws;                                   // 2,048,000 B
    u64* pkeys = (u64*)(ws + 2048000);                       // 80*4096*8 = 2,621,440 B
    u64* cand  = (u64*)(ws + 2048000 + 2621440);             // 64,000 B
    int* gcnt  = (int*)(ws + 2048000 + 2621440 + 64000);     // 320 B

    hipMemsetAsync(gcnt, 0, NCLS * sizeof(int), stream);
    k_compact<<<16, 256, 0, stream>>>(scores, conf_t, pkeys, gcnt);
    k_suppr<<<NB, 256, 0, stream>>>(bboxes, nms_t, suppr);
    k_classnms<<<NCLS, 1024, 0, stream>>>(pkeys, gcnt, suppr, cand);
    k_rank<<<NCLS, 1024, 0, stream>>>(cand, bboxes, (float*)d_out);
}

// Round 8
// 198.925 us; speedup vs baseline: 3.2173x; 1.1996x over previous
//
#include <hip/hip_runtime.h>
#include <stdint.h>

typedef unsigned long long u64;
typedef unsigned int u32;

#define NB    4000            // boxes
#define NCLS  80              // foreground classes
#define ROWW  64              // u64 words per suppression row (4096 bits)
#define MAXI  100             // max instances
#define NKEY  (NCLS * MAXI)   // 8000 candidate keys
#define PCAP  4096            // per-class key-list capacity (stride)
#define SMAX  4096

__device__ __forceinline__ u32 mono_f32(float f) {
    u32 u = __float_as_uint(f);
    return (u & 0x80000000u) ? ~u : (u | 0x80000000u);
}

// ---------------- K0: compaction, one block per (box-chunk, class) ---------
// No loop: load -> ballot -> atomic -> scatter. 1280 blocks for max TLP.
__global__ __launch_bounds__(256) void k_compact(const float* __restrict__ scores,
                                                 const float* __restrict__ conf_t,
                                                 u64* __restrict__ pkeys,
                                                 int* __restrict__ gcnt) {
    const int b    = blockIdx.x * 256 + threadIdx.x;
    const int c    = blockIdx.y;
    const int lane = threadIdx.x & 63;
    const float conf = *conf_t;
    const bool inb = (b < NB);
    const float s = inb ? scores[b * 81 + c + 1] : -1e30f;
    const bool valid = inb && (s > conf);
    const u64 mask = __ballot(valid);
    if (mask) {
        int base = 0;
        if (lane == 0) base = atomicAdd(&gcnt[c], (int)__popcll(mask));
        base = __shfl(base, 0);
        if (valid) {
            const int off = (int)__popcll(mask & ((1ull << lane) - 1ull));
            pkeys[c * PCAP + base + off] =
                ((u64)mono_f32(s) << 32) | (u64)(0xFFFFFFFFu - (u32)b);
        }
    }
}

// ---------------- K1: suppression bitmap, 4 rows per block -----------------
__global__ __launch_bounds__(256) void k_suppr(const float4* __restrict__ boxes,
                                               const float* __restrict__ nms_t,
                                               u64* __restrict__ suppr) {
    const int i0  = blockIdx.x * 4;
    const int tid = threadIdx.x;
    const float t = *nms_t;
    float4 bi[4]; float ai[4];
    #pragma unroll
    for (int r = 0; r < 4; ++r) {
        bi[r] = boxes[i0 + r];
        ai[r] = (bi[r].z - bi[r].x) * (bi[r].w - bi[r].y);
    }
    #pragma unroll
    for (int ch = 0; ch < 16; ++ch) {
        const int j = ch * 256 + tid;
        const bool inb = (j < NB);
        float4 bj = make_float4(0.f, 0.f, 0.f, 0.f);
        float aj = 0.f;
        if (inb) { bj = boxes[j]; aj = (bj.z - bj.x) * (bj.w - bj.y); }
        #pragma unroll
        for (int r = 0; r < 4; ++r) {
            bool bit = false;
            if (inb && j != i0 + r) {
                const float ix1 = fmaxf(bi[r].x, bj.x), iy1 = fmaxf(bi[r].y, bj.y);
                const float ix2 = fminf(bi[r].z, bj.z), iy2 = fminf(bi[r].w, bj.w);
                const float inter = fmaxf(ix2 - ix1, 0.0f) * fmaxf(iy2 - iy1, 0.0f);
                bit = inter / (ai[r] + aj - inter + 1e-9f) > t;
            }
            const u64 m = __ballot(bit);
            if ((tid & 63) == 0) suppr[(size_t)(i0 + r) * ROWW + (j >> 6)] = m;
        }
    }
}

// ---------------- K2: per-class sort (LDS + shfl hybrid) + greedy walk -----
__global__ __launch_bounds__(1024) void k_classnms(const u64* __restrict__ pkeys,
                                                   const int* __restrict__ gcnt,
                                                   const u64* __restrict__ suppr,
                                                   u64* __restrict__ cand) {
    __shared__ u64 skey[SMAX];
    __shared__ unsigned short sbox[SMAX];
    __shared__ int sh_kept;

    const int c    = blockIdx.x;
    const int tid  = threadIdx.x;
    const int lane = tid & 63;

    const int nvalid = gcnt[c];
    int S = 64;
    while (S < nvalid) S <<= 1;           // 64..4096, multiple of 64

    if (tid == 0) sh_kept = 0;
    for (int i = tid; i < nvalid; i += 1024) skey[i] = pkeys[c * PCAP + i];
    for (int i = nvalid + tid; i < S; i += 1024) skey[i] = 0;
    __syncthreads();

    // bitonic sort descending: j>=64 in LDS (conflict-free), j<=32 via shfl
    for (int k2 = 2; k2 <= S; k2 <<= 1) {
        for (int j = k2 >> 1; j >= 64; j >>= 1) {
            for (int p = tid; p < (S >> 1); p += 1024) {
                const int i0 = ((p & ~(j - 1)) << 1) | (p & (j - 1));
                const u64 a = skey[i0], b = skey[i0 | j];
                const bool up = ((i0 & k2) == 0);
                if (up ? (a < b) : (a > b)) { skey[i0] = b; skey[i0 | j] = a; }
            }
            __syncthreads();
        }
        // in-register exchanges for j = 32..1
        for (int base = 0; base < S; base += 1024) {
            const int i = base + tid;
            if (i < S) {                   // S multiple of 64 -> whole waves
                u64 x = skey[i];
                #pragma unroll
                for (int j2 = 32; j2 >= 1; j2 >>= 1) {
                    if (j2 < k2) {
                        const u64 y = __shfl_xor(x, j2);
                        const bool wantmax = (((i & k2) == 0) == ((i & j2) == 0));
                        x = wantmax ? (x > y ? x : y) : (x < y ? x : y);
                    }
                }
                skey[i] = x;
            }
        }
        __syncthreads();
    }

    for (int i = tid; i < S; i += 1024)
        sbox[i] = (unsigned short)(0xFFFFFFFFu - (u32)skey[i]);
    __syncthreads();

    // serial greedy walk on wave 0; kept-set = distributed 4096-bit mask
    if (tid < 64) {
        u64 keptmask = 0;
        int kept = 0;
        if (nvalid > 0) {
            const int last = nvalid - 1;
            const int i1 = (1 <= last) ? 1 : last;
            u64 w_cur = suppr[(size_t)sbox[0] * ROWW + lane];
            u64 w_n1  = suppr[(size_t)sbox[i1] * ROWW + lane];
            for (int p = 0; p < nvalid && kept < MAXI; ++p) {
                const int i2 = (p + 2 <= last) ? p + 2 : last;
                const u64 w_n2 = suppr[(size_t)sbox[i2] * ROWW + lane];
                const bool suppressed = (__ballot((w_cur & keptmask) != 0ull) != 0ull);
                if (!suppressed) {
                    const int b = sbox[p];
                    if (lane == (b >> 6)) keptmask |= (1ull << (b & 63));
                    if (lane == 0) {
                        const u32 mono = (u32)(skey[p] >> 32);
                        const u32 flat = (u32)(c * NB + b);
                        cand[c * MAXI + kept] = ((u64)mono << 32) | (u64)(0xFFFFFFFFu - flat);
                    }
                    kept++;
                }
                w_cur = w_n1; w_n1 = w_n2;
            }
        }
        if (lane == 0) sh_kept = kept;
    }
    __syncthreads();

    const int kept = sh_kept;
    for (int s = tid; s < MAXI; s += 1024)
        if (s >= kept) cand[c * MAXI + s] = 0;
}

// ---------------- K3: rank-by-count top-100 (no sort) ----------------------
__global__ __launch_bounds__(1024) void k_rank(const u64* __restrict__ cand,
                                               const float4* __restrict__ boxes,
                                               float* __restrict__ out) {
    __shared__ u64 keys[NKEY];            // 64,000 B
    __shared__ int sh_T;
    const int c   = blockIdx.x;
    const int tid = threadIdx.x;

    if (tid == 0) sh_T = 0;
    for (int i = tid; i < NKEY; i += 1024) keys[i] = cand[i];
    __syncthreads();

    if (tid < 8 * MAXI) {
        const int ci   = tid >> 3;
        const int part = tid & 7;
        const u64 mine = keys[c * MAXI + ci];
        if (mine != 0ull) {
            int cnt = 0;
            #pragma unroll 8
            for (int m = 0; m < NKEY / 8; ++m)
                cnt += (keys[part + (m << 3)] > mine);
            cnt += __shfl_xor(cnt, 1);
            cnt += __shfl_xor(cnt, 2);
            cnt += __shfl_xor(cnt, 4);
            if (part == 0 && cnt < MAXI) {
                const int rank = cnt;
                const u32 mono = (u32)(mine >> 32);
                if (mono > 0x80000000u) {          // score > 0.0
                    const float s  = __uint_as_float(mono ^ 0x80000000u);
                    const u32 flat = 0xFFFFFFFFu - (u32)mine;
                    const int b    = (int)(flat % NB);
                    const float4 bb = boxes[b];
                    out[rank*5+0] = bb.x; out[rank*5+1] = bb.y;
                    out[rank*5+2] = bb.z; out[rank*5+3] = bb.w;
                    out[rank*5+4] = s;
                    out[500 + rank] = (float)(flat / NB);
                } else {
                    out[rank*5+0] = 0.0f; out[rank*5+1] = 0.0f; out[rank*5+2] = 0.0f;
                    out[rank*5+3] = 0.0f; out[rank*5+4] = 0.0f;
                    out[500 + rank] = -1.0f;
                }
            }
        }
    }

    // block 0: fill default rows [T, 100)
    if (c == 0) {
        int cnt = 0;
        for (int i = tid; i < NKEY; i += 1024) cnt += (keys[i] != 0ull);
        atomicAdd(&sh_T, cnt);
        __syncthreads();
        const int T = sh_T;
        for (int r = T + tid; r < MAXI; r += 1024) {
            out[r*5+0] = 0.0f; out[r*5+1] = 0.0f; out[r*5+2] = 0.0f;
            out[r*5+3] = 0.0f; out[r*5+4] = 0.0f;
            out[500 + r] = -1.0f;
        }
    }
}

extern "C" void kernel_launch(void* const* d_in, const int* in_sizes, int n_in,
                              void* d_out, int out_size, void* d_ws, size_t ws_size,
                              hipStream_t stream) {
    const float4* bboxes = (const float4*)d_in[0];
    const float*  scores = (const float*)d_in[1];
    const float*  conf_t = (const float*)d_in[2];
    const float*  nms_t  = (const float*)d_in[3];

    char* ws = (char*)d_ws;
    u64* suppr = (u64*)ws;                                   // 2,048,000 B
    u64* pkeys = (u64*)(ws + 2048000);                       // 80*4096*8 = 2,621,440 B
    u64* cand  = (u64*)(ws + 2048000 + 2621440);             // 64,000 B
    int* gcnt  = (int*)(ws + 2048000 + 2621440 + 64000);     // 320 B

    hipMemsetAsync(gcnt, 0, NCLS * sizeof(int), stream);
    k_compact<<<dim3(16, NCLS), 256, 0, stream>>>(scores, conf_t, pkeys, gcnt);
    k_suppr<<<NB / 4, 256, 0, stream>>>(bboxes, nms_t, suppr);
    k_classnms<<<NCLS, 1024, 0, stream>>>(pkeys, gcnt, suppr, cand);
    k_rank<<<NCLS, 1024, 0, stream>>>(cand, bboxes, (float*)d_out);
}

// Round 9
// 158.819 us; speedup vs baseline: 4.0297x; 1.2525x over previous
//
#include <hip/hip_runtime.h>
#include <stdint.h>

typedef unsigned long long u64;
typedef unsigned int u32;

#define NB    4000            // boxes
#define NCLS  80              // foreground classes
#define ROWW  64              // u64 words per suppression row (4096 bits)
#define MAXI  100             // max instances
#define NKEY  (NCLS * MAXI)   // 8000 candidate keys
#define PCAP  4096            // per-class key-list capacity (stride)
#define SMAX  4096
#define NSEG  8               // rank segments
#define SEGN  (NKEY / NSEG)   // 1000 keys per segment

__device__ __forceinline__ u32 mono_f32(float f) {
    u32 u = __float_as_uint(f);
    return (u & 0x80000000u) ? ~u : (u | 0x80000000u);
}

// ---------------- K0: compaction, one block per (box-chunk, class) ---------
__global__ __launch_bounds__(256) void k_compact(const float* __restrict__ scores,
                                                 const float* __restrict__ conf_t,
                                                 u64* __restrict__ pkeys,
                                                 int* __restrict__ gcnt) {
    const int b    = blockIdx.x * 256 + threadIdx.x;
    const int c    = blockIdx.y;
    const int wid  = threadIdx.x >> 6;
    const int lane = threadIdx.x & 63;
    __shared__ int wcnt[4];
    __shared__ int bbase;
    const float conf = *conf_t;
    const bool inb = (b < NB);
    const float s = inb ? scores[b * 81 + c + 1] : -1e30f;
    const bool valid = inb && (s > conf);
    const u64 mask = __ballot(valid);
    if (lane == 0) wcnt[wid] = (int)__popcll(mask);
    __syncthreads();
    if (threadIdx.x == 0) {
        const int t0 = wcnt[0], t1 = wcnt[1], t2 = wcnt[2], t3 = wcnt[3];
        const int tot = t0 + t1 + t2 + t3;
        bbase = tot ? atomicAdd(&gcnt[c], tot) : 0;
        wcnt[0] = 0; wcnt[1] = t0; wcnt[2] = t0 + t1; wcnt[3] = t0 + t1 + t2;
    }
    __syncthreads();
    if (valid) {
        const int off = (int)__popcll(mask & ((1ull << lane) - 1ull));
        pkeys[c * PCAP + bbase + wcnt[wid] + off] =
            ((u64)mono_f32(s) << 32) | (u64)(0xFFFFFFFFu - (u32)b);
    }
}

// ---------------- K1: suppression bitmap, 4 rows per block -----------------
__global__ __launch_bounds__(256) void k_suppr(const float4* __restrict__ boxes,
                                               const float* __restrict__ nms_t,
                                               u64* __restrict__ suppr) {
    const int i0  = blockIdx.x * 4;
    const int tid = threadIdx.x;
    const float t = *nms_t;
    float4 bi[4]; float ai[4];
    #pragma unroll
    for (int r = 0; r < 4; ++r) {
        bi[r] = boxes[i0 + r];
        ai[r] = (bi[r].z - bi[r].x) * (bi[r].w - bi[r].y);
    }
    #pragma unroll
    for (int ch = 0; ch < 16; ++ch) {
        const int j = ch * 256 + tid;
        const bool inb = (j < NB);
        float4 bj = make_float4(0.f, 0.f, 0.f, 0.f);
        float aj = 0.f;
        if (inb) { bj = boxes[j]; aj = (bj.z - bj.x) * (bj.w - bj.y); }
        #pragma unroll
        for (int r = 0; r < 4; ++r) {
            bool bit = false;
            if (inb && j != i0 + r) {
                const float ix1 = fmaxf(bi[r].x, bj.x), iy1 = fmaxf(bi[r].y, bj.y);
                const float ix2 = fminf(bi[r].z, bj.z), iy2 = fminf(bi[r].w, bj.w);
                const float inter = fmaxf(ix2 - ix1, 0.0f) * fmaxf(iy2 - iy1, 0.0f);
                bit = inter / (ai[r] + aj - inter + 1e-9f) > t;
            }
            const u64 m = __ballot(bit);
            if ((tid & 63) == 0) suppr[(size_t)(i0 + r) * ROWW + (j >> 6)] = m;
        }
    }
}

// ---------------- K2: per-class sort + greedy walk (16-deep ping-pong) -----
__global__ __launch_bounds__(1024) void k_classnms(const u64* __restrict__ pkeys,
                                                   const int* __restrict__ gcnt,
                                                   const u64* __restrict__ suppr,
                                                   u64* __restrict__ cand) {
    __shared__ u64 skey[SMAX];
    __shared__ unsigned short sbox[SMAX];
    __shared__ int sh_kept;

    const int c    = blockIdx.x;
    const int tid  = threadIdx.x;
    const int lane = tid & 63;

    const int nvalid = gcnt[c];
    int S = 64;
    while (S < nvalid) S <<= 1;           // 64..4096, multiple of 64

    if (tid == 0) sh_kept = 0;
    for (int i = tid; i < nvalid; i += 1024) skey[i] = pkeys[c * PCAP + i];
    for (int i = nvalid + tid; i < S; i += 1024) skey[i] = 0;
    __syncthreads();

    // bitonic sort descending: j>=64 in LDS (conflict-free), j<=32 via shfl
    for (int k2 = 2; k2 <= S; k2 <<= 1) {
        for (int j = k2 >> 1; j >= 64; j >>= 1) {
            for (int p = tid; p < (S >> 1); p += 1024) {
                const int i0 = ((p & ~(j - 1)) << 1) | (p & (j - 1));
                const u64 a = skey[i0], b = skey[i0 | j];
                const bool up = ((i0 & k2) == 0);
                if (up ? (a < b) : (a > b)) { skey[i0] = b; skey[i0 | j] = a; }
            }
            __syncthreads();
        }
        for (int base = 0; base < S; base += 1024) {
            const int i = base + tid;
            if (i < S) {
                u64 x = skey[i];
                #pragma unroll
                for (int j2 = 32; j2 >= 1; j2 >>= 1) {
                    if (j2 < k2) {
                        const u64 y = __shfl_xor(x, j2);
                        const bool wantmax = (((i & k2) == 0) == ((i & j2) == 0));
                        x = wantmax ? (x > y ? x : y) : (x < y ? x : y);
                    }
                }
                skey[i] = x;
            }
        }
        __syncthreads();
    }

    for (int i = tid; i < S; i += 1024)
        sbox[i] = (unsigned short)(0xFFFFFFFFu - (u32)skey[i]);
    __syncthreads();

    // serial greedy walk, wave 0; 16-deep ping-pong register prefetch
    if (tid < 64) {
        u64 keptmask = 0;
        int kept = 0;
        if (nvalid > 0) {
            const int last = nvalid - 1;
            u64 wA[16], wB[16];
            #pragma unroll
            for (int q = 0; q < 16; ++q) {
                const int idx = (q <= last) ? q : last;
                wA[q] = suppr[(size_t)sbox[idx] * ROWW + lane];
            }
            for (int cs = 0; cs < nvalid && kept < MAXI; cs += 32) {
                #pragma unroll
                for (int q = 0; q < 16; ++q) {
                    const int want = cs + 16 + q;
                    const int idx = (want <= last) ? want : last;
                    wB[q] = suppr[(size_t)sbox[idx] * ROWW + lane];
                }
                #pragma unroll
                for (int q = 0; q < 16; ++q) {
                    const int p = cs + q;
                    if (p < nvalid && kept < MAXI) {
                        const bool sup = (__ballot((wA[q] & keptmask) != 0ull) != 0ull);
                        if (!sup) {
                            const int b = sbox[p];
                            if (lane == (b >> 6)) keptmask |= (1ull << (b & 63));
                            if (lane == 0) {
                                const u32 mono = (u32)(skey[p] >> 32);
                                const u32 flat = (u32)(c * NB + b);
                                cand[c * MAXI + kept] =
                                    ((u64)mono << 32) | (u64)(0xFFFFFFFFu - flat);
                            }
                            kept++;
                        }
                    }
                }
                #pragma unroll
                for (int q = 0; q < 16; ++q) {
                    const int want = cs + 32 + q;
                    const int idx = (want <= last) ? want : last;
                    wA[q] = suppr[(size_t)sbox[idx] * ROWW + lane];
                }
                #pragma unroll
                for (int q = 0; q < 16; ++q) {
                    const int p = cs + 16 + q;
                    if (p < nvalid && kept < MAXI) {
                        const bool sup = (__ballot((wB[q] & keptmask) != 0ull) != 0ull);
                        if (!sup) {
                            const int b = sbox[p];
                            if (lane == (b >> 6)) keptmask |= (1ull << (b & 63));
                            if (lane == 0) {
                                const u32 mono = (u32)(skey[p] >> 32);
                                const u32 flat = (u32)(c * NB + b);
                                cand[c * MAXI + kept] =
                                    ((u64)mono << 32) | (u64)(0xFFFFFFFFu - flat);
                            }
                            kept++;
                        }
                    }
                }
            }
        }
        if (lane == 0) sh_kept = kept;
    }
    __syncthreads();

    const int kept = sh_kept;
    for (int s = tid; s < MAXI; s += 1024)
        if (s >= kept) cand[c * MAXI + s] = 0;
}

// ---------------- K3a: segmented rank-by-count -----------------------------
// block (seg s, class c): partial rank of class c's candidates vs segment s
__global__ __launch_bounds__(256) void k_rankseg(const u64* __restrict__ cand,
                                                 int* __restrict__ grank) {
    __shared__ u64 keys[SEGN];            // 8 KB
    const int s   = blockIdx.x;
    const int c   = blockIdx.y;
    const int tid = threadIdx.x;

    for (int i = tid; i < SEGN; i += 256) keys[i] = cand[s * SEGN + i];
    __syncthreads();

    if (tid < 2 * MAXI) {
        const int ci   = tid >> 1;
        const int half = tid & 1;
        const u64 mine = cand[c * MAXI + ci];
        if (mine != 0ull) {
            int cnt = 0;
            const int beg = half * (SEGN / 2), end = beg + (SEGN / 2);
            #pragma unroll 4
            for (int m = beg; m < end; ++m) cnt += (keys[m] > mine);
            cnt += __shfl_xor(cnt, 1);
            if (half == 0 && cnt > 0) atomicAdd(&grank[c * MAXI + ci], cnt);
        }
    }
}

// ---------------- K3b: emit top-100 rows -----------------------------------
__global__ __launch_bounds__(1024) void k_emit(const u64* __restrict__ cand,
                                               const int* __restrict__ grank,
                                               const float4* __restrict__ boxes,
                                               float* __restrict__ out) {
    const int tid = threadIdx.x;
    // defaults first
    if (tid < MAXI) {
        out[tid*5+0] = 0.0f; out[tid*5+1] = 0.0f; out[tid*5+2] = 0.0f;
        out[tid*5+3] = 0.0f; out[tid*5+4] = 0.0f;
        out[500 + tid] = -1.0f;
    }
    __syncthreads();
    for (int i = tid; i < NKEY; i += 1024) {
        const u64 k = cand[i];
        if (k == 0ull) continue;
        const int r = grank[i];
        if (r >= MAXI) continue;
        const u32 mono = (u32)(k >> 32);
        const float sc  = __uint_as_float(mono ^ 0x80000000u);
        const u32 flat = 0xFFFFFFFFu - (u32)k;
        const int b    = (int)(flat % NB);
        const float4 bb = boxes[b];
        out[r*5+0] = bb.x; out[r*5+1] = bb.y;
        out[r*5+2] = bb.z; out[r*5+3] = bb.w;
        out[r*5+4] = sc;
        out[500 + r] = (float)(flat / NB);
    }
}

extern "C" void kernel_launch(void* const* d_in, const int* in_sizes, int n_in,
                              void* d_out, int out_size, void* d_ws, size_t ws_size,
                              hipStream_t stream) {
    const float4* bboxes = (const float4*)d_in[0];
    const float*  scores = (const float*)d_in[1];
    const float*  conf_t = (const float*)d_in[2];
    const float*  nms_t  = (const float*)d_in[3];

    char* ws = (char*)d_ws;
    u64* suppr = (u64*)ws;                                   // 2,048,000 B
    u64* pkeys = (u64*)(ws + 2048000);                       // 2,621,440 B
    u64* cand  = (u64*)(ws + 2048000 + 2621440);             // 64,000 B
    int* gcnt  = (int*)(ws + 2048000 + 2621440 + 64000);     // 320 B
    int* grank = (int*)(ws + 2048000 + 2621440 + 64000 + 320); // 32,000 B

    hipMemsetAsync(gcnt, 0, 320 + NKEY * sizeof(int), stream); // gcnt + grank
    k_compact<<<dim3(16, NCLS), 256, 0, stream>>>(scores, conf_t, pkeys, gcnt);
    k_suppr<<<NB / 4, 256, 0, stream>>>(bboxes, nms_t, suppr);
    k_classnms<<<NCLS, 1024, 0, stream>>>(pkeys, gcnt, suppr, cand);
    k_rankseg<<<dim3(NSEG, NCLS), 256, 0, stream>>>(cand, grank);
    k_emit<<<1, 1024, 0, stream>>>(cand, grank, bboxes, (float*)d_out);
}

// Round 10
// 135.730 us; speedup vs baseline: 4.7152x; 1.1701x over previous
//
#include <hip/hip_runtime.h>
#include <stdint.h>

typedef unsigned long long u64;
typedef unsigned int u32;

#define NB    4000            // boxes
#define NCLS  80              // foreground classes
#define ROWW  64              // u64 words per suppression row (4096 bits)
#define MAXI  100             // max instances
#define NKEY  (NCLS * MAXI)   // 8000 candidate keys
#define PCAP  4096            // per-class key-list capacity (stride)
#define SMAX  4096
#define NSEG  8               // rank segments
#define SEGN  (NKEY / NSEG)   // 1000 keys per segment
#define SELT  448             // selection target (top-M superset)
#define NTH   512             // classnms block size

__device__ __forceinline__ u32 mono_f32(float f) {
    u32 u = __float_as_uint(f);
    return (u & 0x80000000u) ? ~u : (u | 0x80000000u);
}

// wave-0 helper: find crossing bin B (descending) where suffix count reaches T.
// hist: 1024 bins. Returns B and A = #keys in bins > B. Requires total >= T.
__device__ __forceinline__ void find_cross(const u32* hist, int T, int lane,
                                           int* outB, int* outA) {
    int running = 0, B = -1, A = 0;
    for (int g = 0; g < 16 && B < 0; ++g) {
        const int d = 1023 - (g * 64 + lane);     // lane 0 = highest bin
        const int cnt = (int)hist[d];
        int pre = cnt;
        #pragma unroll
        for (int off = 1; off < 64; off <<= 1) {
            const int v = __shfl_up(pre, off);
            if (lane >= off) pre += v;
        }
        const int incl = running + pre;
        const int excl = incl - cnt;
        const u64 hm = __ballot(excl < T && incl >= T);
        if (hm != 0ull) {
            const int hl = (int)__builtin_ctzll(hm);
            B = __shfl(d, hl);
            A = __shfl(excl, hl);
        }
        running = __shfl(incl, 63);
    }
    *outB = B; *outA = A;
}

// ---------------- K1: suppression bitmap, 4 rows/block; block0 zeroes cnts -
__global__ __launch_bounds__(256) void k_suppr(const float4* __restrict__ boxes,
                                               const float* __restrict__ nms_t,
                                               u64* __restrict__ suppr,
                                               int* __restrict__ zero_region) {
    if (blockIdx.x == 0) {     // gcnt[80] + grank[8000], contiguous
        for (int i = threadIdx.x; i < NCLS + NKEY; i += 256) zero_region[i] = 0;
    }
    const int i0  = blockIdx.x * 4;
    const int tid = threadIdx.x;
    const float t = *nms_t;
    float4 bi[4]; float ai[4];
    #pragma unroll
    for (int r = 0; r < 4; ++r) {
        bi[r] = boxes[i0 + r];
        ai[r] = (bi[r].z - bi[r].x) * (bi[r].w - bi[r].y);
    }
    #pragma unroll
    for (int ch = 0; ch < 16; ++ch) {
        const int j = ch * 256 + tid;
        const bool inb = (j < NB);
        float4 bj = make_float4(0.f, 0.f, 0.f, 0.f);
        float aj = 0.f;
        if (inb) { bj = boxes[j]; aj = (bj.z - bj.x) * (bj.w - bj.y); }
        #pragma unroll
        for (int r = 0; r < 4; ++r) {
            bool bit = false;
            if (inb && j != i0 + r) {
                const float ix1 = fmaxf(bi[r].x, bj.x), iy1 = fmaxf(bi[r].y, bj.y);
                const float ix2 = fminf(bi[r].z, bj.z), iy2 = fminf(bi[r].w, bj.w);
                const float inter = fmaxf(ix2 - ix1, 0.0f) * fmaxf(iy2 - iy1, 0.0f);
                bit = inter / (ai[r] + aj - inter + 1e-9f) > t;
            }
            const u64 m = __ballot(bit);
            if ((tid & 63) == 0) suppr[(size_t)(i0 + r) * ROWW + (j >> 6)] = m;
        }
    }
}

// ---------------- K0: compaction, one block per (box-chunk, class) ---------
__global__ __launch_bounds__(256) void k_compact(const float* __restrict__ scores,
                                                 const float* __restrict__ conf_t,
                                                 u64* __restrict__ pkeys,
                                                 int* __restrict__ gcnt) {
    const int b    = blockIdx.x * 256 + threadIdx.x;
    const int c    = blockIdx.y;
    const int wid  = threadIdx.x >> 6;
    const int lane = threadIdx.x & 63;
    __shared__ int wcnt[4];
    __shared__ int bbase;
    const float conf = *conf_t;
    const bool inb = (b < NB);
    const float s = inb ? scores[b * 81 + c + 1] : -1e30f;
    const bool valid = inb && (s > conf);
    const u64 mask = __ballot(valid);
    if (lane == 0) wcnt[wid] = (int)__popcll(mask);
    __syncthreads();
    if (threadIdx.x == 0) {
        const int t0 = wcnt[0], t1 = wcnt[1], t2 = wcnt[2], t3 = wcnt[3];
        const int tot = t0 + t1 + t2 + t3;
        bbase = tot ? atomicAdd(&gcnt[c], tot) : 0;
        wcnt[0] = 0; wcnt[1] = t0; wcnt[2] = t0 + t1; wcnt[3] = t0 + t1 + t2;
    }
    __syncthreads();
    if (valid) {
        const int off = (int)__popcll(mask & ((1ull << lane) - 1ull));
        pkeys[c * PCAP + bbase + wcnt[wid] + off] =
            ((u64)mono_f32(s) << 32) | (u64)(0xFFFFFFFFu - (u32)b);
    }
}

// ---------------- K2: radix-select top-M + sort + greedy walk --------------
__global__ __launch_bounds__(NTH) void k_classnms(const u64* __restrict__ pkeys,
                                                  const int* __restrict__ gcnt,
                                                  const u64* __restrict__ suppr,
                                                  u64* __restrict__ cand) {
    __shared__ u64 skey[SMAX];                 // 32 KB
    __shared__ unsigned short sbox[SMAX];      // 8 KB (aliased as hist pre-sort)
    __shared__ int sh_kept, sh_M, sh_B, sh_A, sh_B2;

    u32* hist = (u32*)sbox;                    // 1024 u32 bins (4 KB of the 8)

    const int c    = blockIdx.x;
    const int tid  = threadIdx.x;
    const int lane = tid & 63;

    const int nvalid = gcnt[c];

    // each thread owns slots tid + q*NTH (global pkeys, held in regs)
    u64 own[8];
    #pragma unroll
    for (int q = 0; q < 8; ++q) {
        const int idx = tid + q * NTH;
        own[q] = (idx < nvalid) ? pkeys[c * PCAP + idx] : 0ull;
    }

    bool full = (nvalid <= 512);
    int kept = 0;

    for (int attempt = 0; attempt < 2; ++attempt) {
        int M;
        if (!full) {
            // ---- level-1 histogram on key bits [63:54] ----
            for (int i = tid; i < 1024; i += NTH) hist[i] = 0;
            if (tid == 0) sh_M = 0;
            __syncthreads();
            #pragma unroll
            for (int q = 0; q < 8; ++q)
                if (tid + q * NTH < nvalid)
                    atomicAdd(&hist[(u32)(own[q] >> 54) & 1023u], 1u);
            __syncthreads();
            if (tid < 64) {
                int B, A;
                find_cross(hist, SELT, lane, &B, &A);
                if (lane == 0) { sh_B = B; sh_A = A; }
            }
            __syncthreads();
            const int B = sh_B, A = sh_A;
            // ---- level-2 histogram on bits [53:44], keys in bin B ----
            for (int i = tid; i < 1024; i += NTH) hist[i] = 0;
            __syncthreads();
            #pragma unroll
            for (int q = 0; q < 8; ++q)
                if (tid + q * NTH < nvalid &&
                    ((u32)(own[q] >> 54) & 1023u) == (u32)B)
                    atomicAdd(&hist[(u32)(own[q] >> 44) & 1023u], 1u);
            __syncthreads();
            if (tid < 64) {
                int B2, A2;
                find_cross(hist, SELT - A, lane, &B2, &A2);
                if (lane == 0) sh_B2 = B2;
            }
            __syncthreads();
            const int B2 = sh_B2;
            // ---- compact selected keys into skey[0..M) ----
            #pragma unroll
            for (int q = 0; q < 8; ++q) {
                bool sel = false;
                if (tid + q * NTH < nvalid) {
                    const int d = (int)((u32)(own[q] >> 54) & 1023u);
                    sel = (d > B) ||
                          (d == B && (int)((u32)(own[q] >> 44) & 1023u) >= B2);
                }
                const u64 bm = __ballot(sel);
                int wbase = 0;
                if (lane == 0 && bm) wbase = atomicAdd(&sh_M, (int)__popcll(bm));
                wbase = __shfl(wbase, 0);
                if (sel)
                    skey[wbase + (int)__popcll(bm & ((1ull << lane) - 1ull))] = own[q];
            }
            __syncthreads();
            M = sh_M;
        } else {
            #pragma unroll
            for (int q = 0; q < 8; ++q) {
                const int idx = tid + q * NTH;
                if (idx < nvalid) skey[idx] = own[q];
            }
            M = nvalid;
            __syncthreads();
        }

        int S = 64;
        while (S < M) S <<= 1;
        for (int i = M + tid; i < S; i += NTH) skey[i] = 0;
        __syncthreads();

        // ---- bitonic sort descending: j>=64 in LDS, j<=32 via shfl ----
        for (int k2 = 2; k2 <= S; k2 <<= 1) {
            for (int j = k2 >> 1; j >= 64; j >>= 1) {
                for (int p = tid; p < (S >> 1); p += NTH) {
                    const int i0 = ((p & ~(j - 1)) << 1) | (p & (j - 1));
                    const u64 a = skey[i0], b = skey[i0 | j];
                    const bool up = ((i0 & k2) == 0);
                    if (up ? (a < b) : (a > b)) { skey[i0] = b; skey[i0 | j] = a; }
                }
                __syncthreads();
            }
            for (int base = 0; base < S; base += NTH) {
                const int i = base + tid;
                if (i < S) {
                    u64 x = skey[i];
                    #pragma unroll
                    for (int j2 = 32; j2 >= 1; j2 >>= 1) {
                        if (j2 < k2) {
                            const u64 y = __shfl_xor(x, j2);
                            const bool wantmax = (((i & k2) == 0) == ((i & j2) == 0));
                            x = wantmax ? (x > y ? x : y) : (x < y ? x : y);
                        }
                    }
                    skey[i] = x;
                }
            }
            __syncthreads();
        }

        for (int i = tid; i < S; i += NTH)
            sbox[i] = (unsigned short)(0xFFFFFFFFu - (u32)skey[i]);
        __syncthreads();

        // ---- serial greedy walk, wave 0; 16-deep ping-pong prefetch ----
        if (tid < 64) {
            u64 keptmask = 0;
            int kp = 0;
            if (M > 0) {
                const int last = M - 1;
                u64 wA[16], wB[16];
                #pragma unroll
                for (int q = 0; q < 16; ++q) {
                    const int idx = (q <= last) ? q : last;
                    wA[q] = suppr[(size_t)sbox[idx] * ROWW + lane];
                }
                for (int cs = 0; cs < M && kp < MAXI; cs += 32) {
                    #pragma unroll
                    for (int q = 0; q < 16; ++q) {
                        const int want = cs + 16 + q;
                        const int idx = (want <= last) ? want : last;
                        wB[q] = suppr[(size_t)sbox[idx] * ROWW + lane];
                    }
                    #pragma unroll
                    for (int q = 0; q < 16; ++q) {
                        const int p = cs + q;
                        if (p < M && kp < MAXI) {
                            const bool sup = (__ballot((wA[q] & keptmask) != 0ull) != 0ull);
                            if (!sup) {
                                const int b = sbox[p];
                                if (lane == (b >> 6)) keptmask |= (1ull << (b & 63));
                                if (lane == 0) {
                                    const u32 mono = (u32)(skey[p] >> 32);
                                    const u32 flat = (u32)(c * NB + b);
                                    cand[c * MAXI + kp] =
                                        ((u64)mono << 32) | (u64)(0xFFFFFFFFu - flat);
                                }
                                kp++;
                            }
                        }
                    }
                    #pragma unroll
                    for (int q = 0; q < 16; ++q) {
                        const int want = cs + 32 + q;
                        const int idx = (want <= last) ? want : last;
                        wA[q] = suppr[(size_t)sbox[idx] * ROWW + lane];
                    }
                    #pragma unroll
                    for (int q = 0; q < 16; ++q) {
                        const int p = cs + 16 + q;
                        if (p < M && kp < MAXI) {
                            const bool sup = (__ballot((wB[q] & keptmask) != 0ull) != 0ull);
                            if (!sup) {
                                const int b = sbox[p];
                                if (lane == (b >> 6)) keptmask |= (1ull << (b & 63));
                                if (lane == 0) {
                                    const u32 mono = (u32)(skey[p] >> 32);
                                    const u32 flat = (u32)(c * NB + b);
                                    cand[c * MAXI + kp] =
                                        ((u64)mono << 32) | (u64)(0xFFFFFFFFu - flat);
                                }
                                kp++;
                            }
                        }
                    }
                }
            }
            if (lane == 0) sh_kept = kp;
        }
        __syncthreads();
        kept = sh_kept;

        if (kept >= MAXI || full) break;   // exact: walked the true top-M prefix
        full = true;                       // rare fallback: full sort + re-walk
    }

    for (int s = tid; s < MAXI; s += NTH)
        if (s >= kept) cand[c * MAXI + s] = 0;
}

// ---------------- K3a: segmented rank-by-count -----------------------------
__global__ __launch_bounds__(256) void k_rankseg(const u64* __restrict__ cand,
                                                 int* __restrict__ grank) {
    __shared__ u64 keys[SEGN];            // 8 KB
    const int s   = blockIdx.x;
    const int c   = blockIdx.y;
    const int tid = threadIdx.x;

    for (int i = tid; i < SEGN; i += 256) keys[i] = cand[s * SEGN + i];
    __syncthreads();

    if (tid < 2 * MAXI) {
        const int ci   = tid >> 1;
        const int half = tid & 1;
        const u64 mine = cand[c * MAXI + ci];
        if (mine != 0ull) {
            int cnt = 0;
            const int beg = half * (SEGN / 2), end = beg + (SEGN / 2);
            #pragma unroll 4
            for (int m = beg; m < end; ++m) cnt += (keys[m] > mine);
            cnt += __shfl_xor(cnt, 1);
            if (half == 0 && cnt > 0) atomicAdd(&grank[c * MAXI + ci], cnt);
        }
    }
}

// ---------------- K3b: emit top-100 rows -----------------------------------
__global__ __launch_bounds__(1024) void k_emit(const u64* __restrict__ cand,
                                               const int* __restrict__ grank,
                                               const float4* __restrict__ boxes,
                                               float* __restrict__ out) {
    const int tid = threadIdx.x;
    if (tid < MAXI) {
        out[tid*5+0] = 0.0f; out[tid*5+1] = 0.0f; out[tid*5+2] = 0.0f;
        out[tid*5+3] = 0.0f; out[tid*5+4] = 0.0f;
        out[500 + tid] = -1.0f;
    }
    __syncthreads();
    for (int i = tid; i < NKEY; i += 1024) {
        const u64 k = cand[i];
        if (k == 0ull) continue;
        const int r = grank[i];
        if (r >= MAXI) continue;
        const u32 mono = (u32)(k >> 32);
        const float sc  = __uint_as_float(mono ^ 0x80000000u);
        const u32 flat = 0xFFFFFFFFu - (u32)k;
        const int b    = (int)(flat % NB);
        const float4 bb = boxes[b];
        out[r*5+0] = bb.x; out[r*5+1] = bb.y;
        out[r*5+2] = bb.z; out[r*5+3] = bb.w;
        out[r*5+4] = sc;
        out[500 + r] = (float)(flat / NB);
    }
}

extern "C" void kernel_launch(void* const* d_in, const int* in_sizes, int n_in,
                              void* d_out, int out_size, void* d_ws, size_t ws_size,
                              hipStream_t stream) {
    const float4* bboxes = (const float4*)d_in[0];
    const float*  scores = (const float*)d_in[1];
    const float*  conf_t = (const float*)d_in[2];
    const float*  nms_t  = (const float*)d_in[3];

    char* ws = (char*)d_ws;
    u64* suppr = (u64*)ws;                                     // 2,048,000 B
    u64* pkeys = (u64*)(ws + 2048000);                         // 2,621,440 B
    u64* cand  = (u64*)(ws + 2048000 + 2621440);               // 64,000 B
    int* gcnt  = (int*)(ws + 2048000 + 2621440 + 64000);       // 320 B
    int* grank = (int*)(ws + 2048000 + 2621440 + 64000 + 320); // 32,000 B (contiguous after gcnt)

    k_suppr<<<NB / 4, 256, 0, stream>>>(bboxes, nms_t, suppr, gcnt);  // block 0 zeroes gcnt+grank
    k_compact<<<dim3(16, NCLS), 256, 0, stream>>>(scores, conf_t, pkeys, gcnt);
    k_classnms<<<NCLS, NTH, 0, stream>>>(pkeys, gcnt, suppr, cand);
    k_rankseg<<<dim3(NSEG, NCLS), 256, 0, stream>>>(cand, grank);
    k_emit<<<1, 1024, 0, stream>>>(cand, grank, bboxes, (float*)d_out);
}

// Round 11
// 124.311 us; speedup vs baseline: 5.1484x; 1.0919x over previous
//
#include <hip/hip_runtime.h>
#include <stdint.h>

typedef unsigned long long u64;
typedef unsigned int u32;

#define NB    4000            // boxes
#define NBP   4096            // padded (16*256)
#define NCLS  80              // foreground classes
#define ROWW  64              // u64 words per suppression row
#define MAXI  100             // max instances
#define NKEY  (NCLS * MAXI)   // 8000 candidate keys
#define SMAX  4096
#define SELT  448             // classnms selection target
#define NTH   512             // classnms block size

__device__ __forceinline__ u32 mono_f32(float f) {
    u32 u = __float_as_uint(f);
    return (u & 0x80000000u) ? ~u : (u | 0x80000000u);
}

// wave helper: descending scan of 1024-bin hist; find bin B where suffix count
// reaches T; A = #keys in bins > B. Requires hist total >= T >= 1.
__device__ __forceinline__ void find_cross(const u32* hist, int T, int lane,
                                           int* outB, int* outA) {
    int running = 0, B = -1, A = 0;
    for (int g = 0; g < 16 && B < 0; ++g) {
        const int d = 1023 - (g * 64 + lane);     // lane 0 = highest bin
        const int cnt = (int)hist[d];
        int pre = cnt;
        #pragma unroll
        for (int off = 1; off < 64; off <<= 1) {
            const int v = __shfl_up(pre, off);
            if (lane >= off) pre += v;
        }
        const int incl = running + pre;
        const int excl = incl - cnt;
        const u64 hm = __ballot(excl < T && incl >= T);
        if (hm != 0ull) {
            const int hl = (int)__builtin_ctzll(hm);
            B = __shfl(d, hl);
            A = __shfl(excl, hl);
        }
        running = __shfl(incl, 63);
    }
    *outB = B; *outA = A;
}

// ---------------- K1: fused suppression bitmap + dense score keys ----------
// blocks [0,1000): suppr, 4 rows each. blocks [1000,2280): pkeys[c][b] write.
__global__ __launch_bounds__(256) void k_pre(const float4* __restrict__ boxes,
                                             const float* __restrict__ scores,
                                             const float* __restrict__ conf_t,
                                             const float* __restrict__ nms_t,
                                             u64* __restrict__ suppr,
                                             u64* __restrict__ pkeys) {
    const int tid = threadIdx.x;
    if (blockIdx.x < NB / 4) {
        const int i0  = blockIdx.x * 4;
        const float t = *nms_t;
        float4 bi[4]; float ai[4];
        #pragma unroll
        for (int r = 0; r < 4; ++r) {
            bi[r] = boxes[i0 + r];
            ai[r] = (bi[r].z - bi[r].x) * (bi[r].w - bi[r].y);
        }
        #pragma unroll
        for (int ch = 0; ch < 16; ++ch) {
            const int j = ch * 256 + tid;
            const bool inb = (j < NB);
            float4 bj = make_float4(0.f, 0.f, 0.f, 0.f);
            float aj = 0.f;
            if (inb) { bj = boxes[j]; aj = (bj.z - bj.x) * (bj.w - bj.y); }
            #pragma unroll
            for (int r = 0; r < 4; ++r) {
                bool bit = false;
                if (inb && j != i0 + r) {
                    const float ix1 = fmaxf(bi[r].x, bj.x), iy1 = fmaxf(bi[r].y, bj.y);
                    const float ix2 = fminf(bi[r].z, bj.z), iy2 = fminf(bi[r].w, bj.w);
                    const float inter = fmaxf(ix2 - ix1, 0.0f) * fmaxf(iy2 - iy1, 0.0f);
                    bit = inter / (ai[r] + aj - inter + 1e-9f) > t;
                }
                const u64 m = __ballot(bit);
                if ((tid & 63) == 0) suppr[(size_t)(i0 + r) * ROWW + (j >> 6)] = m;
            }
        }
    } else {
        const int idx = blockIdx.x - NB / 4;      // 0..1279
        const int c   = idx >> 4;
        const int b   = ((idx & 15) << 8) | tid;  // 0..4095
        const float conf = *conf_t;
        u64 key = 0;
        if (b < NB) {
            const float s = scores[b * 81 + c + 1];
            if (s > conf)
                key = ((u64)mono_f32(s) << 32) | (u64)(0xFFFFFFFFu - (u32)b);
        }
        pkeys[c * NBP + b] = key;                 // b in [NB,NBP) -> 0
    }
}

// ---------------- K2: radix-select top-M + sort + greedy walk --------------
__global__ __launch_bounds__(NTH) void k_classnms(const u64* __restrict__ pkeys,
                                                  const u64* __restrict__ suppr,
                                                  u64* __restrict__ cand) {
    __shared__ u64 skey[SMAX];                 // 32 KB
    __shared__ unsigned short sbox[SMAX];      // 8 KB (hist aliased pre-sort)
    __shared__ int wsum[8];
    __shared__ int sh_kept, sh_M, sh_B, sh_A, sh_B2, sh_nvalid;

    u32* hist = (u32*)sbox;                    // 1024 u32 bins

    const int c    = blockIdx.x;
    const int tid  = threadIdx.x;
    const int lane = tid & 63;
    const int wid  = tid >> 6;

    // dense load; count nonzero
    u64 own[8];
    int cnt = 0;
    #pragma unroll
    for (int q = 0; q < 8; ++q) {
        own[q] = pkeys[c * NBP + tid + q * NTH];
        cnt += (own[q] != 0ull);
    }
    #pragma unroll
    for (int off = 1; off < 64; off <<= 1) cnt += __shfl_xor(cnt, off);
    if (lane == 0) wsum[wid] = cnt;
    __syncthreads();
    if (tid == 0) {
        int t = 0;
        #pragma unroll
        for (int w = 0; w < 8; ++w) t += wsum[w];
        sh_nvalid = t;
    }
    __syncthreads();
    const int nvalid = sh_nvalid;

    bool full = (nvalid <= 512);
    int kept = 0;

    for (int attempt = 0; attempt < 2; ++attempt) {
        int M;
        if (!full) {
            // ---- level-1 histogram on key bits [63:54] ----
            for (int i = tid; i < 1024; i += NTH) hist[i] = 0;
            if (tid == 0) sh_M = 0;
            __syncthreads();
            #pragma unroll
            for (int q = 0; q < 8; ++q)
                if (own[q] != 0ull)
                    atomicAdd(&hist[(u32)(own[q] >> 54) & 1023u], 1u);
            __syncthreads();
            if (tid < 64) {
                int B, A;
                find_cross(hist, SELT, lane, &B, &A);
                if (lane == 0) { sh_B = B; sh_A = A; }
            }
            __syncthreads();
            const int B = sh_B, A = sh_A;
            // ---- level-2 histogram on bits [53:44], keys in bin B ----
            for (int i = tid; i < 1024; i += NTH) hist[i] = 0;
            __syncthreads();
            #pragma unroll
            for (int q = 0; q < 8; ++q)
                if (own[q] != 0ull && ((u32)(own[q] >> 54) & 1023u) == (u32)B)
                    atomicAdd(&hist[(u32)(own[q] >> 44) & 1023u], 1u);
            __syncthreads();
            if (tid < 64) {
                int B2, A2;
                find_cross(hist, SELT - A, lane, &B2, &A2);
                if (lane == 0) sh_B2 = B2;
            }
            __syncthreads();
            const int B2 = sh_B2;
            // ---- compact selected keys into skey[0..M) ----
            #pragma unroll
            for (int q = 0; q < 8; ++q) {
                bool sel = false;
                if (own[q] != 0ull) {
                    const int d = (int)((u32)(own[q] >> 54) & 1023u);
                    sel = (d > B) ||
                          (d == B && (int)((u32)(own[q] >> 44) & 1023u) >= B2);
                }
                const u64 bm = __ballot(sel);
                int wbase = 0;
                if (lane == 0 && bm) wbase = atomicAdd(&sh_M, (int)__popcll(bm));
                wbase = __shfl(wbase, 0);
                if (sel)
                    skey[wbase + (int)__popcll(bm & ((1ull << lane) - 1ull))] = own[q];
            }
            __syncthreads();
            M = sh_M;
        } else {
            // compact ALL nonzero keys
            if (tid == 0) sh_M = 0;
            __syncthreads();
            #pragma unroll
            for (int q = 0; q < 8; ++q) {
                const bool sel = (own[q] != 0ull);
                const u64 bm = __ballot(sel);
                int wbase = 0;
                if (lane == 0 && bm) wbase = atomicAdd(&sh_M, (int)__popcll(bm));
                wbase = __shfl(wbase, 0);
                if (sel)
                    skey[wbase + (int)__popcll(bm & ((1ull << lane) - 1ull))] = own[q];
            }
            __syncthreads();
            M = sh_M;                          // == nvalid
        }

        int S = 64;
        while (S < M) S <<= 1;
        for (int i = M + tid; i < S; i += NTH) skey[i] = 0;
        __syncthreads();

        // ---- bitonic sort descending: j>=64 in LDS, j<=32 via shfl ----
        for (int k2 = 2; k2 <= S; k2 <<= 1) {
            for (int j = k2 >> 1; j >= 64; j >>= 1) {
                for (int p = tid; p < (S >> 1); p += NTH) {
                    const int i0 = ((p & ~(j - 1)) << 1) | (p & (j - 1));
                    const u64 a = skey[i0], b = skey[i0 | j];
                    const bool up = ((i0 & k2) == 0);
                    if (up ? (a < b) : (a > b)) { skey[i0] = b; skey[i0 | j] = a; }
                }
                __syncthreads();
            }
            for (int base = 0; base < S; base += NTH) {
                const int i = base + tid;
                if (i < S) {
                    u64 x = skey[i];
                    #pragma unroll
                    for (int j2 = 32; j2 >= 1; j2 >>= 1) {
                        if (j2 < k2) {
                            const u64 y = __shfl_xor(x, j2);
                            const bool wantmax = (((i & k2) == 0) == ((i & j2) == 0));
                            x = wantmax ? (x > y ? x : y) : (x < y ? x : y);
                        }
                    }
                    skey[i] = x;
                }
            }
            __syncthreads();
        }

        for (int i = tid; i < S; i += NTH)
            sbox[i] = (unsigned short)(0xFFFFFFFFu - (u32)skey[i]);
        __syncthreads();

        // ---- serial greedy walk, wave 0; 16-deep ping-pong prefetch ----
        if (tid < 64) {
            u64 keptmask = 0;
            int kp = 0;
            if (M > 0) {
                const int last = M - 1;
                u64 wA[16], wB[16];
                #pragma unroll
                for (int q = 0; q < 16; ++q) {
                    const int idx = (q <= last) ? q : last;
                    wA[q] = suppr[(size_t)sbox[idx] * ROWW + lane];
                }
                for (int cs = 0; cs < M && kp < MAXI; cs += 32) {
                    #pragma unroll
                    for (int q = 0; q < 16; ++q) {
                        const int want = cs + 16 + q;
                        const int idx = (want <= last) ? want : last;
                        wB[q] = suppr[(size_t)sbox[idx] * ROWW + lane];
                    }
                    #pragma unroll
                    for (int q = 0; q < 16; ++q) {
                        const int p = cs + q;
                        if (p < M && kp < MAXI) {
                            const bool sup = (__ballot((wA[q] & keptmask) != 0ull) != 0ull);
                            if (!sup) {
                                const int b = sbox[p];
                                if (lane == (b >> 6)) keptmask |= (1ull << (b & 63));
                                if (lane == 0) {
                                    const u32 mono = (u32)(skey[p] >> 32);
                                    const u32 flat = (u32)(c * NB + b);
                                    cand[c * MAXI + kp] =
                                        ((u64)mono << 32) | (u64)(0xFFFFFFFFu - flat);
                                }
                                kp++;
                            }
                        }
                    }
                    #pragma unroll
                    for (int q = 0; q < 16; ++q) {
                        const int want = cs + 32 + q;
                        const int idx = (want <= last) ? want : last;
                        wA[q] = suppr[(size_t)sbox[idx] * ROWW + lane];
                    }
                    #pragma unroll
                    for (int q = 0; q < 16; ++q) {
                        const int p = cs + 16 + q;
                        if (p < M && kp < MAXI) {
                            const bool sup = (__ballot((wB[q] & keptmask) != 0ull) != 0ull);
                            if (!sup) {
                                const int b = sbox[p];
                                if (lane == (b >> 6)) keptmask |= (1ull << (b & 63));
                                if (lane == 0) {
                                    const u32 mono = (u32)(skey[p] >> 32);
                                    const u32 flat = (u32)(c * NB + b);
                                    cand[c * MAXI + kp] =
                                        ((u64)mono << 32) | (u64)(0xFFFFFFFFu - flat);
                                }
                                kp++;
                            }
                        }
                    }
                }
            }
            if (lane == 0) sh_kept = kp;
        }
        __syncthreads();
        kept = sh_kept;

        if (kept >= MAXI || full) break;   // exact: walked true top-M prefix
        full = true;                       // rare fallback: full sort + re-walk
    }

    for (int s = tid; s < MAXI; s += NTH)
        if (s >= kept) cand[c * MAXI + s] = 0;
}

// ---------------- K3: global top-100 via iterative radix-select + emit -----
__global__ __launch_bounds__(1024) void k_final(const u64* __restrict__ cand,
                                                const float4* __restrict__ boxes,
                                                float* __restrict__ out) {
    __shared__ u32 hist[1024];
    __shared__ u64 sel[256];
    __shared__ int wsum[16];
    __shared__ int sh_total, sh_A, sh_B, sh_bits, sh_M, sh_cnt;
    __shared__ u64 sh_prefix;

    const int tid  = threadIdx.x;
    const int lane = tid & 63;
    const int wid  = tid >> 6;

    u64 myk[8];
    int cnt = 0;
    #pragma unroll
    for (int q = 0; q < 8; ++q) {
        const int i = tid + (q << 10);
        myk[q] = (i < NKEY) ? cand[i] : 0ull;
        cnt += (myk[q] != 0ull);
    }
    #pragma unroll
    for (int off = 1; off < 64; off <<= 1) cnt += __shfl_xor(cnt, off);
    if (lane == 0) wsum[wid] = cnt;
    if (tid < 256) sel[tid] = 0;
    __syncthreads();
    if (tid == 0) {
        int t = 0;
        #pragma unroll
        for (int w = 0; w < 16; ++w) t += wsum[w];
        sh_total = t; sh_A = 0; sh_bits = 0; sh_prefix = 0; sh_cnt = 0;
    }
    __syncthreads();
    const int total = sh_total;
    const int Tt = (total < MAXI) ? total : MAXI;

    if (total > 0) {
        // iterative 10-bit radix-select until selected count M <= 256
        for (int lvl = 0; lvl < 6; ++lvl) {
            hist[tid & 1023] = 0;              // 1024 threads cover all bins
            __syncthreads();
            const int bits = sh_bits;
            const u64 pref = sh_prefix;
            const int shift = 54 - bits;
            #pragma unroll
            for (int q = 0; q < 8; ++q) {
                const u64 k = myk[q];
                if (k != 0ull && (bits == 0 || (k >> (64 - bits)) == pref))
                    atomicAdd(&hist[(u32)(k >> shift) & 1023u], 1u);
            }
            __syncthreads();
            if (tid < 64) {
                const int T = Tt - sh_A;
                int B, A;
                find_cross(hist, T, lane, &B, &A);
                if (lane == 0) { sh_B = B; sh_A += A; }
            }
            __syncthreads();
            if (tid == 0) {
                sh_M = sh_A + (int)hist[sh_B];
                sh_prefix = (sh_prefix << 10) | (u32)sh_B;
                sh_bits += 10;
            }
            __syncthreads();
            if (sh_M <= 256) break;            // provably reached by lvl 5
        }
        // compact selected (prefix >= sh_prefix) into sel[0..M)
        const int bits = sh_bits;
        const u64 pref = sh_prefix;
        #pragma unroll
        for (int q = 0; q < 8; ++q) {
            const u64 k = myk[q];
            const bool s = (k != 0ull) && ((k >> (64 - bits)) >= pref);
            const u64 bm = __ballot(s);
            int wbase = 0;
            if (lane == 0 && bm) wbase = atomicAdd(&sh_cnt, (int)__popcll(bm));
            wbase = __shfl(wbase, 0);
            if (s) sel[wbase + (int)__popcll(bm & ((1ull << lane) - 1ull))] = k;
        }
    }

    // defaults first, then rank-by-count scatter (unique keys -> unique ranks)
    if (tid < MAXI) {
        out[tid*5+0] = 0.0f; out[tid*5+1] = 0.0f; out[tid*5+2] = 0.0f;
        out[tid*5+3] = 0.0f; out[tid*5+4] = 0.0f;
        out[500 + tid] = -1.0f;
    }
    __syncthreads();
    if (tid < 256) {
        const u64 my = sel[tid];
        if (my != 0ull) {
            int r = 0;
            for (int j = 0; j < 256; ++j) r += (sel[j] > my);
            if (r < MAXI) {
                const u32 mono = (u32)(my >> 32);
                const float sc = __uint_as_float(mono ^ 0x80000000u);
                const u32 flat = 0xFFFFFFFFu - (u32)my;
                const int b    = (int)(flat % NB);
                const float4 bb = boxes[b];
                out[r*5+0] = bb.x; out[r*5+1] = bb.y;
                out[r*5+2] = bb.z; out[r*5+3] = bb.w;
                out[r*5+4] = sc;
                out[500 + r] = (float)(flat / NB);
            }
        }
    }
}

extern "C" void kernel_launch(void* const* d_in, const int* in_sizes, int n_in,
                              void* d_out, int out_size, void* d_ws, size_t ws_size,
                              hipStream_t stream) {
    const float4* bboxes = (const float4*)d_in[0];
    const float*  scores = (const float*)d_in[1];
    const float*  conf_t = (const float*)d_in[2];
    const float*  nms_t  = (const float*)d_in[3];

    char* ws = (char*)d_ws;
    u64* suppr = (u64*)ws;                       // 2,048,000 B
    u64* pkeys = (u64*)(ws + 2048000);           // 80*4096*8 = 2,621,440 B
    u64* cand  = (u64*)(ws + 2048000 + 2621440); // 64,000 B

    k_pre<<<NB / 4 + 16 * NCLS, 256, 0, stream>>>(bboxes, scores, conf_t, nms_t,
                                                  suppr, pkeys);
    k_classnms<<<NCLS, NTH, 0, stream>>>(pkeys, suppr, cand);
    k_final<<<1, 1024, 0, stream>>>(cand, bboxes, (float*)d_out);
}